// Round 3
// baseline (36.924 us; speedup 1.0000x reference)
//
#include <hip/hip_runtime.h>
#include <stdint.h>

// ---------------------------------------------------------------------------
// SelectiveDropout: out[b,d] = in[b,d] * scale[d]
//   scale[d] = 1 unless d in neuron_indices; for listed columns,
//   scale = (u < 0.1) ? 0 : 1/0.9 with u from jax.random.uniform(key(42),(2048,))
//   duplicates: last write wins.
//
// RNG: Threefry-2x32, 20 rounds, key = (0, 42), partitionable counter mode
// (verified bit-exact vs jax in round 1).
// ---------------------------------------------------------------------------

#define D_DIM 4096

typedef float f32x4 __attribute__((ext_vector_type(4)));  // native vector:
// __builtin_nontemporal_load/store accept pointers to these (not HIP float4).

__device__ __forceinline__ uint32_t rotl32(uint32_t v, uint32_t n) {
  return (v << n) | (v >> (32u - n));
}

__device__ __forceinline__ void threefry2x32(uint32_t x0, uint32_t x1,
                                             uint32_t& o0, uint32_t& o1) {
  const uint32_t ks0 = 0u;
  const uint32_t ks1 = 42u;
  const uint32_t ks2 = 0u ^ 42u ^ 0x1BD11BDAu;

  x0 += ks0;
  x1 += ks1;

#define TF_GROUP(a, b, c, d)                           \
  x0 += x1; x1 = rotl32(x1, a); x1 ^= x0;              \
  x0 += x1; x1 = rotl32(x1, b); x1 ^= x0;              \
  x0 += x1; x1 = rotl32(x1, c); x1 ^= x0;              \
  x0 += x1; x1 = rotl32(x1, d); x1 ^= x0;

  TF_GROUP(13, 15, 26, 6)  x0 += ks1; x1 += ks2 + 1u;
  TF_GROUP(17, 29, 16, 24) x0 += ks2; x1 += ks0 + 2u;
  TF_GROUP(13, 15, 26, 6)  x0 += ks0; x1 += ks1 + 3u;
  TF_GROUP(17, 29, 16, 24) x0 += ks1; x1 += ks2 + 4u;
  TF_GROUP(13, 15, 26, 6)  x0 += ks2; x1 += ks0 + 5u;
#undef TF_GROUP

  o0 = x0;
  o1 = x1;
}

__device__ __forceinline__ float jax_uniform_at(int i) {
  uint32_t o0, o1;
  threefry2x32(0u, (uint32_t)i, o0, o1);  // counter = i (64-bit iota), hi=0
  uint32_t bits = o0 ^ o1;
  uint32_t fb = (bits >> 9) | 0x3F800000u;
  return __uint_as_float(fb) - 1.0f;
}

// Single-block setup kernel: builds scale[D] via one packed LDS array.
// packed[col] = max over writes of (i<<1 | keep); init -1 (= untouched).
__global__ __launch_bounds__(1024) void build_scale_kernel(
    const int* __restrict__ idx, int n, f32x4* __restrict__ scale_g) {
  __shared__ int packed[D_DIM];
  const int t = threadIdx.x;

  for (int d = t; d < D_DIM; d += 1024) packed[d] = -1;
  __syncthreads();

  for (int i = t; i < n; i += 1024) {
    int col = idx[i];
    float u = jax_uniform_at(i);
    int keep = (u < 0.1f) ? 0 : 1;
    atomicMax(&packed[col], (i << 1) | keep);  // max i wins (last write wins)
  }
  __syncthreads();

  const float inv_keep = (float)(1.0 / (1.0 - 0.1));
  for (int d4 = t; d4 < D_DIM / 4; d4 += 1024) {
    f32x4 s;
    for (int j = 0; j < 4; ++j) {
      int p = packed[d4 * 4 + j];
      s[j] = (p < 0) ? 1.0f : ((p & 1) ? inv_keep : 0.0f);
    }
    scale_g[d4] = s;
  }
}

// Streaming multiply. Grid stride 524288 == 0 mod 1024 -> scale index is
// per-thread constant; exactly 8 float4 per thread, fully unrolled.
__global__ __launch_bounds__(256) void apply_scale_kernel(
    const f32x4* __restrict__ in, const f32x4* __restrict__ scale4,
    f32x4* __restrict__ out, int total4) {
  const int tid = blockIdx.x * 256 + threadIdx.x;
  const int stride = gridDim.x * 256;

  if (total4 == stride * 8) {
    // fast path: hoisted scale, 8 loads in flight, then 8 mul+stores
    const f32x4 s = scale4[tid & 1023];
    f32x4 v[8];
#pragma unroll
    for (int k = 0; k < 8; ++k)
      v[k] = __builtin_nontemporal_load(&in[tid + k * stride]);
#pragma unroll
    for (int k = 0; k < 8; ++k) {
      v[k] *= s;
      __builtin_nontemporal_store(v[k], &out[tid + k * stride]);
    }
  } else {
    for (int e = tid; e < total4; e += stride) {
      f32x4 v = in[e];
      v *= scale4[e & 1023];
      out[e] = v;
    }
  }
}

extern "C" void kernel_launch(void* const* d_in, const int* in_sizes, int n_in,
                              void* d_out, int out_size, void* d_ws, size_t ws_size,
                              hipStream_t stream) {
  const float* in = (const float*)d_in[0];
  const int* idx = (const int*)d_in[1];
  float* out = (float*)d_out;
  float* scale = (float*)d_ws;  // D_DIM floats of scratch

  const int n_idx = in_sizes[1];    // 2048
  const int total = in_sizes[0];    // B*D = 16,777,216
  const int total4 = total / 4;

  hipLaunchKernelGGL(build_scale_kernel, dim3(1), dim3(1024), 0, stream,
                     idx, n_idx, (f32x4*)scale);

  const int blocks = 2048;  // 8 blocks/CU -> 8192 waves = full residency
  hipLaunchKernelGGL(apply_scale_kernel, dim3(blocks), dim3(256), 0, stream,
                     (const f32x4*)in, (const f32x4*)scale, (f32x4*)out,
                     total4);
}

// Round 4
// 32.711 us; speedup vs baseline: 1.1288x; 1.1288x over previous
//
#include <hip/hip_runtime.h>
#include <stdint.h>

// ---------------------------------------------------------------------------
// SelectiveDropout: out[b,d] = in[b,d] * scale[d]
//   scale[d] = 1 unless d in neuron_indices; for listed columns,
//   scale = (u < 0.1) ? 0 : 1/0.9 with u from jax.random.uniform(key(42),(2048,))
//   duplicates: last write wins.
//
// RNG: Threefry-2x32, 20 rounds, key = (0, 42), partitionable counter mode
// (verified bit-exact vs jax in round 1).
//
// Round-3 lesson: NO nontemporal hints here. Input (64 MB) is L3-resident
// across timed graph replays; nt bypasses L2/L3 and cost +13 us on apply.
// ---------------------------------------------------------------------------

#define D_DIM 4096

typedef float f32x4 __attribute__((ext_vector_type(4)));

__device__ __forceinline__ uint32_t rotl32(uint32_t v, uint32_t n) {
  return (v << n) | (v >> (32u - n));
}

__device__ __forceinline__ void threefry2x32(uint32_t x0, uint32_t x1,
                                             uint32_t& o0, uint32_t& o1) {
  const uint32_t ks0 = 0u;
  const uint32_t ks1 = 42u;
  const uint32_t ks2 = 0u ^ 42u ^ 0x1BD11BDAu;

  x0 += ks0;
  x1 += ks1;

#define TF_GROUP(a, b, c, d)                           \
  x0 += x1; x1 = rotl32(x1, a); x1 ^= x0;              \
  x0 += x1; x1 = rotl32(x1, b); x1 ^= x0;              \
  x0 += x1; x1 = rotl32(x1, c); x1 ^= x0;              \
  x0 += x1; x1 = rotl32(x1, d); x1 ^= x0;

  TF_GROUP(13, 15, 26, 6)  x0 += ks1; x1 += ks2 + 1u;
  TF_GROUP(17, 29, 16, 24) x0 += ks2; x1 += ks0 + 2u;
  TF_GROUP(13, 15, 26, 6)  x0 += ks0; x1 += ks1 + 3u;
  TF_GROUP(17, 29, 16, 24) x0 += ks1; x1 += ks2 + 4u;
  TF_GROUP(13, 15, 26, 6)  x0 += ks2; x1 += ks0 + 5u;
#undef TF_GROUP

  o0 = x0;
  o1 = x1;
}

__device__ __forceinline__ float jax_uniform_at(int i) {
  uint32_t o0, o1;
  threefry2x32(0u, (uint32_t)i, o0, o1);  // counter = i (64-bit iota), hi=0
  uint32_t bits = o0 ^ o1;
  uint32_t fb = (bits >> 9) | 0x3F800000u;
  return __uint_as_float(fb) - 1.0f;
}

// Single-block setup kernel: builds scale[D] via one packed LDS array.
// packed[col] = max over writes of (i<<1 | keep); init -1 (= untouched).
__global__ __launch_bounds__(1024) void build_scale_kernel(
    const int* __restrict__ idx, int n, f32x4* __restrict__ scale_g) {
  __shared__ int packed[D_DIM];
  const int t = threadIdx.x;

  for (int d = t; d < D_DIM; d += 1024) packed[d] = -1;
  __syncthreads();

  for (int i = t; i < n; i += 1024) {
    int col = idx[i];
    float u = jax_uniform_at(i);
    int keep = (u < 0.1f) ? 0 : 1;
    atomicMax(&packed[col], (i << 1) | keep);  // max i wins (last write wins)
  }
  __syncthreads();

  const float inv_keep = (float)(1.0 / (1.0 - 0.1));
  for (int d4 = t; d4 < D_DIM / 4; d4 += 1024) {
    f32x4 s;
    for (int j = 0; j < 4; ++j) {
      int p = packed[d4 * 4 + j];
      s[j] = (p < 0) ? 1.0f : ((p & 1) ? inv_keep : 0.0f);
    }
    scale_g[d4] = s;
  }
}

// Streaming multiply. Grid stride 524288 == 0 mod 1024 -> scale index is
// per-thread constant (hoisted); exactly 8 f32x4 per thread, fully unrolled.
// Plain (temporal) loads/stores: input stays L3-resident across replays.
__global__ __launch_bounds__(256) void apply_scale_kernel(
    const f32x4* __restrict__ in, const f32x4* __restrict__ scale4,
    f32x4* __restrict__ out, int total4) {
  const int tid = blockIdx.x * 256 + threadIdx.x;
  const int stride = gridDim.x * 256;

  if (total4 == stride * 8) {
    const f32x4 s = scale4[tid & 1023];
#pragma unroll
    for (int k = 0; k < 8; ++k) {
      f32x4 v = in[tid + k * stride];
      v *= s;
      out[tid + k * stride] = v;
    }
  } else {
    for (int e = tid; e < total4; e += stride) {
      f32x4 v = in[e];
      v *= scale4[e & 1023];
      out[e] = v;
    }
  }
}

extern "C" void kernel_launch(void* const* d_in, const int* in_sizes, int n_in,
                              void* d_out, int out_size, void* d_ws, size_t ws_size,
                              hipStream_t stream) {
  const float* in = (const float*)d_in[0];
  const int* idx = (const int*)d_in[1];
  float* out = (float*)d_out;
  float* scale = (float*)d_ws;  // D_DIM floats of scratch

  const int n_idx = in_sizes[1];    // 2048
  const int total = in_sizes[0];    // B*D = 16,777,216
  const int total4 = total / 4;

  hipLaunchKernelGGL(build_scale_kernel, dim3(1), dim3(1024), 0, stream,
                     idx, n_idx, (f32x4*)scale);

  const int blocks = 2048;  // 8 blocks/CU -> 8192 waves = full residency
  hipLaunchKernelGGL(apply_scale_kernel, dim3(blocks), dim3(256), 0, stream,
                     (const f32x4*)in, (const f32x4*)scale, (f32x4*)out,
                     total4);
}

// Round 5
// 28.818 us; speedup vs baseline: 1.2813x; 1.1351x over previous
//
#include <hip/hip_runtime.h>
#include <stdint.h>

// ---------------------------------------------------------------------------
// SelectiveDropout, fused single-kernel version.
//   out[b,d] = in[b,d] * scale[d]
//   scale[d] = 1 unless d in neuron_indices; listed columns get
//   (u < 0.1) ? 0 : 1/0.9, u = jax.random.uniform(key(42), (2048,)),
//   duplicates last-write-wins. RNG: Threefry-2x32(20 rounds, key=(0,42)),
//   partitionable counter mode (bit-exact vs jax, verified round 1).
//
// Fusion: every block rebuilds the 4096-entry scale vector in LDS
// (2048 hashes, ~1.2us of VALU across the chip, hidden under input-load
// latency). Load-issue order: idx loads FIRST, then the 8 input f32x4
// loads, so the hash's vmcnt wait leaves the input loads in flight.
// Raw s_barrier + lgkmcnt(0) only (NOT __syncthreads, which drains
// vmcnt(0) and would serialize hash after the input stream).
//
// Round-3 lesson: no nontemporal hints (L2/L3 residency matters here).
// ---------------------------------------------------------------------------

#define D_DIM 4096

typedef float f32x4 __attribute__((ext_vector_type(4)));
typedef int i32x4 __attribute__((ext_vector_type(4)));

__device__ __forceinline__ uint32_t rotl32(uint32_t v, uint32_t n) {
  return (v << n) | (v >> (32u - n));
}

__device__ __forceinline__ void threefry2x32(uint32_t x0, uint32_t x1,
                                             uint32_t& o0, uint32_t& o1) {
  const uint32_t ks0 = 0u;
  const uint32_t ks1 = 42u;
  const uint32_t ks2 = 0u ^ 42u ^ 0x1BD11BDAu;

  x0 += ks0;
  x1 += ks1;

#define TF_GROUP(a, b, c, d)                           \
  x0 += x1; x1 = rotl32(x1, a); x1 ^= x0;              \
  x0 += x1; x1 = rotl32(x1, b); x1 ^= x0;              \
  x0 += x1; x1 = rotl32(x1, c); x1 ^= x0;              \
  x0 += x1; x1 = rotl32(x1, d); x1 ^= x0;

  TF_GROUP(13, 15, 26, 6)  x0 += ks1; x1 += ks2 + 1u;
  TF_GROUP(17, 29, 16, 24) x0 += ks2; x1 += ks0 + 2u;
  TF_GROUP(13, 15, 26, 6)  x0 += ks0; x1 += ks1 + 3u;
  TF_GROUP(17, 29, 16, 24) x0 += ks1; x1 += ks2 + 4u;
  TF_GROUP(13, 15, 26, 6)  x0 += ks2; x1 += ks0 + 5u;
#undef TF_GROUP

  o0 = x0;
  o1 = x1;
}

__device__ __forceinline__ int keep_bit(int i) {
  uint32_t o0, o1;
  threefry2x32(0u, (uint32_t)i, o0, o1);
  uint32_t bits = o0 ^ o1;
  float u = __uint_as_float((bits >> 9) | 0x3F800000u) - 1.0f;
  return (u < 0.1f) ? 0 : 1;
}

__global__ __launch_bounds__(256) void selective_dropout_fused(
    const f32x4* __restrict__ in, const int* __restrict__ idx, int n,
    f32x4* __restrict__ out, int total4) {
  __shared__ int packed[D_DIM];  // max over writes of (i<<1 | keep); -1 = untouched
  const int t = threadIdx.x;
  const int tid = blockIdx.x * 256 + t;
  const int stride = gridDim.x * 256;
  const float inv_keep = (float)(1.0 / (1.0 - 0.1));
  i32x4* p4 = (i32x4*)packed;

  if (n == 2048 && total4 == stride * 8) {
    // --- phase A: issue idx loads FIRST (2 x dwordx4 per thread) ---
    i32x4 c0 = *(const i32x4*)&idx[t * 8];
    i32x4 c1 = *(const i32x4*)&idx[t * 8 + 4];
    __builtin_amdgcn_sched_barrier(0);  // pin: idx issues before input loads

    // --- phase B: issue all 8 input loads (stay in flight through hash) ---
    f32x4 v[8];
#pragma unroll
    for (int k = 0; k < 8; ++k) v[k] = in[tid + k * stride];

    // --- phase C: LDS init ---
#pragma unroll
    for (int k = 0; k < 4; ++k) {
      i32x4 m1;
      m1[0] = -1; m1[1] = -1; m1[2] = -1; m1[3] = -1;
      p4[t + k * 256] = m1;
    }
    asm volatile("s_waitcnt lgkmcnt(0)" ::: "memory");
    __builtin_amdgcn_s_barrier();  // LDS-only barrier; input loads stay in flight

    // --- phase D: hash + scatter (vmcnt waits only for idx loads) ---
#pragma unroll
    for (int k = 0; k < 8; ++k) {
      int i = t * 8 + k;
      int col = (k < 4) ? c0[k] : c1[k - 4];
      atomicMax(&packed[col], (i << 1) | keep_bit(i));
    }
    asm volatile("s_waitcnt lgkmcnt(0)" ::: "memory");
    __builtin_amdgcn_s_barrier();

    // --- phase E: per-thread scale (grid stride % 1024 == 0 -> constant col4) ---
    i32x4 pk = p4[tid & 1023];
    f32x4 s;
#pragma unroll
    for (int j = 0; j < 4; ++j)
      s[j] = (pk[j] < 0) ? 1.0f : ((pk[j] & 1) ? inv_keep : 0.0f);

    // --- phase F: multiply + store as loads land ---
#pragma unroll
    for (int k = 0; k < 8; ++k) {
      v[k] *= s;
      out[tid + k * stride] = v[k];
    }
  } else {
    // Generic fallback (any n / shape): simple build + grid-stride apply.
    for (int d = t; d < D_DIM; d += 256) packed[d] = -1;
    __syncthreads();
    for (int i = t; i < n; i += 256) {
      atomicMax(&packed[idx[i]], (i << 1) | keep_bit(i));
    }
    __syncthreads();
    for (int e = tid; e < total4; e += stride) {
      i32x4 pk = p4[e & (D_DIM / 4 - 1)];
      f32x4 s;
#pragma unroll
      for (int j = 0; j < 4; ++j)
        s[j] = (pk[j] < 0) ? 1.0f : ((pk[j] & 1) ? inv_keep : 0.0f);
      f32x4 x = in[e];
      x *= s;
      out[e] = x;
    }
  }
}

extern "C" void kernel_launch(void* const* d_in, const int* in_sizes, int n_in,
                              void* d_out, int out_size, void* d_ws, size_t ws_size,
                              hipStream_t stream) {
  const float* in = (const float*)d_in[0];
  const int* idx = (const int*)d_in[1];
  float* out = (float*)d_out;

  const int n_idx = in_sizes[1];    // 2048
  const int total = in_sizes[0];    // B*D = 16,777,216
  const int total4 = total / 4;

  const int blocks = 2048;  // 8 blocks/CU -> full residency
  hipLaunchKernelGGL(selective_dropout_fused, dim3(blocks), dim3(256), 0,
                     stream, (const f32x4*)in, idx, n_idx, (f32x4*)out,
                     total4);
}

// Round 6
// 28.082 us; speedup vs baseline: 1.3149x; 1.0262x over previous
//
#include <hip/hip_runtime.h>
#include <stdint.h>

// ---------------------------------------------------------------------------
// SelectiveDropout, fused single-kernel, quarter-compacted hash.
//   out[b,d] = in[b,d] * scale[d]
//   scale[d] = 1 unless d in neuron_indices; listed columns get
//   (u < 0.1) ? 0 : 1/0.9, u = jax.random.uniform(key(42), (2048,)),
//   duplicates last-write-wins. RNG: Threefry-2x32(20 rounds, key=(0,42)),
//   partitionable counter mode (bit-exact vs jax, verified round 1).
//
// Structure: grid stride == 0 mod 1024, so block b only reads scale
// columns [ (b&3)*1024, +1024 ) -- one quarter of D. Each block ballot-
// compacts the ~512 relevant indices into LDS, then hashes ONLY those
// (2/thread instead of 8/thread): hash head ~4us -> ~1.3us while keeping
// 2048-block occupancy. Input loads are issued before the hash and stay
// in flight across LDS-only barriers (raw s_barrier + lgkmcnt(0), never
// __syncthreads which drains vmcnt).
//
// Round-3 lesson: no nontemporal hints (L2/L3 residency matters here).
// ---------------------------------------------------------------------------

#define D_DIM 4096

typedef float f32x4 __attribute__((ext_vector_type(4)));
typedef int i32x4 __attribute__((ext_vector_type(4)));

__device__ __forceinline__ uint32_t rotl32(uint32_t v, uint32_t n) {
  return (v << n) | (v >> (32u - n));
}

__device__ __forceinline__ void threefry2x32(uint32_t x0, uint32_t x1,
                                             uint32_t& o0, uint32_t& o1) {
  const uint32_t ks0 = 0u;
  const uint32_t ks1 = 42u;
  const uint32_t ks2 = 0u ^ 42u ^ 0x1BD11BDAu;

  x0 += ks0;
  x1 += ks1;

#define TF_GROUP(a, b, c, d)                           \
  x0 += x1; x1 = rotl32(x1, a); x1 ^= x0;              \
  x0 += x1; x1 = rotl32(x1, b); x1 ^= x0;              \
  x0 += x1; x1 = rotl32(x1, c); x1 ^= x0;              \
  x0 += x1; x1 = rotl32(x1, d); x1 ^= x0;

  TF_GROUP(13, 15, 26, 6)  x0 += ks1; x1 += ks2 + 1u;
  TF_GROUP(17, 29, 16, 24) x0 += ks2; x1 += ks0 + 2u;
  TF_GROUP(13, 15, 26, 6)  x0 += ks0; x1 += ks1 + 3u;
  TF_GROUP(17, 29, 16, 24) x0 += ks1; x1 += ks2 + 4u;
  TF_GROUP(13, 15, 26, 6)  x0 += ks2; x1 += ks0 + 5u;
#undef TF_GROUP

  o0 = x0;
  o1 = x1;
}

__device__ __forceinline__ int keep_bit(int i) {
  uint32_t o0, o1;
  threefry2x32(0u, (uint32_t)i, o0, o1);
  uint32_t bits = o0 ^ o1;
  float u = __uint_as_float((bits >> 9) | 0x3F800000u) - 1.0f;
  return (u < 0.1f) ? 0 : 1;
}

__global__ __launch_bounds__(256) void selective_dropout_fused(
    const f32x4* __restrict__ in, const int* __restrict__ idx, int n,
    f32x4* __restrict__ out, int total4) {
  // Shared carve-up. Fast path: packed[0..1023], comp[1024..3071], cnt[3072].
  // Fallback: packed uses all 4096.
  __shared__ int lds[D_DIM];
  const int t = threadIdx.x;
  const int tid = blockIdx.x * 256 + t;
  const int stride = gridDim.x * 256;
  const float inv_keep = (float)(1.0 / (1.0 - 0.1));

  if (n == 2048 && total4 == stride * 8) {
    int* packed = lds;        // [1024] this block's quarter: max (i<<1|keep)
    int* comp = lds + 1024;   // [2048] compacted (i<<12 | d) entries
    int* cnt = lds + 3072;
    const int q = blockIdx.x & 3;  // quarter: tid&1023 = q*256 + t

    // --- A: idx loads first (oldest vmem -> hash wait leaves inputs in flight)
    i32x4 c0 = *(const i32x4*)&idx[t * 8];
    i32x4 c1 = *(const i32x4*)&idx[t * 8 + 4];
    __builtin_amdgcn_sched_barrier(0);

    // --- B: issue all 8 input loads
    f32x4 v[8];
#pragma unroll
    for (int k = 0; k < 8; ++k) v[k] = in[tid + k * stride];
    __builtin_amdgcn_sched_barrier(0);

    // --- C: init packed + counter
    {
      i32x4 m1;
      m1[0] = -1; m1[1] = -1; m1[2] = -1; m1[3] = -1;
      ((i32x4*)packed)[t] = m1;
    }
    if (t == 0) *cnt = 0;
    asm volatile("s_waitcnt lgkmcnt(0)" ::: "memory");
    __builtin_amdgcn_s_barrier();

    // --- D: ballot-compact indices belonging to this block's quarter
    const int lane = t & 63;
    const unsigned long long lt_mask = (lane == 0) ? 0ull : (~0ull >> (64 - lane));
#pragma unroll
    for (int k = 0; k < 8; ++k) {
      int i = t * 8 + k;
      int d = (k < 4) ? c0[k] : c1[k - 4];
      bool match = ((d >> 10) == q);
      unsigned long long mask = __ballot(match);
      int base = 0;
      if (lane == 0) base = atomicAdd(cnt, __popcll(mask));
      base = __shfl(base, 0);
      if (match) {
        int prefix = __popcll(mask & lt_mask);
        comp[base + prefix] = (i << 12) | d;  // i<2048 (11b), d<4096 (12b)
      }
    }
    asm volatile("s_waitcnt lgkmcnt(0)" ::: "memory");
    __builtin_amdgcn_s_barrier();

    // --- E: hash only the compacted list (~512 -> 2/thread), scatter
    int m = *cnt;
    for (int j = t; j < m; j += 256) {
      int e = comp[j];
      int i = e >> 12;
      int d = e & 4095;
      atomicMax(&packed[d & 1023], (i << 1) | keep_bit(i));
    }
    asm volatile("s_waitcnt lgkmcnt(0)" ::: "memory");
    __builtin_amdgcn_s_barrier();

    // --- F: per-thread scale: local col4 index == t
    i32x4 pk = ((i32x4*)packed)[t];
    f32x4 s;
#pragma unroll
    for (int j = 0; j < 4; ++j)
      s[j] = (pk[j] < 0) ? 1.0f : ((pk[j] & 1) ? inv_keep : 0.0f);

    // --- G: multiply + store as loads land
#pragma unroll
    for (int k = 0; k < 8; ++k) {
      v[k] *= s;
      out[tid + k * stride] = v[k];
    }
  } else {
    // Generic fallback: full scatter into 4096-entry packed, grid-stride apply.
    int* packed = lds;
    for (int d = t; d < D_DIM; d += 256) packed[d] = -1;
    __syncthreads();
    for (int i = t; i < n; i += 256) {
      atomicMax(&packed[idx[i]], (i << 1) | keep_bit(i));
    }
    __syncthreads();
    for (int e = tid; e < total4; e += stride) {
      i32x4 pk = ((i32x4*)packed)[e & (D_DIM / 4 - 1)];
      f32x4 s;
#pragma unroll
      for (int j = 0; j < 4; ++j)
        s[j] = (pk[j] < 0) ? 1.0f : ((pk[j] & 1) ? inv_keep : 0.0f);
      f32x4 x = in[e];
      x *= s;
      out[e] = x;
    }
  }
}

extern "C" void kernel_launch(void* const* d_in, const int* in_sizes, int n_in,
                              void* d_out, int out_size, void* d_ws, size_t ws_size,
                              hipStream_t stream) {
  const float* in = (const float*)d_in[0];
  const int* idx = (const int*)d_in[1];
  float* out = (float*)d_out;

  const int n_idx = in_sizes[1];    // 2048
  const int total = in_sizes[0];    // B*D = 16,777,216
  const int total4 = total / 4;

  const int blocks = 2048;  // 8 blocks/CU -> full residency
  hipLaunchKernelGGL(selective_dropout_fused, dim3(blocks), dim3(256), 0,
                     stream, (const f32x4*)in, idx, n_idx, (f32x4*)out,
                     total4);
}

// Round 7
// 26.982 us; speedup vs baseline: 1.3685x; 1.0408x over previous
//
#include <hip/hip_runtime.h>
#include <stdint.h>

// ---------------------------------------------------------------------------
// SelectiveDropout, fused single-kernel, compile-time RNG table.
//   out[b,d] = in[b,d] * scale[d]
//   scale[d] = 1 unless d in neuron_indices; listed columns get
//   (u < 0.1) ? 0 : 1/0.9, u = jax.random.uniform(key(42), (2048,)),
//   duplicates last-write-wins.
//
// Key insight this round: keep_bit(i) depends ONLY on i (Threefry of the
// fixed key(42)), not on runtime data -> all 2048 keep bits are constexpr-
// evaluated at COMPILE time into a 64-word table. Float compare folded to
// integer: u < 0.1f  <=>  (bits>>9) <= 838860   (u = m*2^-23 exact,
// 0.1f = 838860.8125 * 2^-23). Verified bit-exact vs jax in rounds 1-6
// (absmax 0.0) with the identical Threefry implementation.
//
// Structure: 1024 blocks x 512 threads (4 blocks/CU, exactly resident).
// Grid stride 524288 == 0 mod 1024 -> block b only reads scale columns
// [ (b&1)*2048, +2048 ). Head per block: load idx quarter (1 dwordx4) +
// 1 table word, direct filtered scatter into 2048-entry LDS winner array
// (no hash, no compaction), 2 LDS-only barriers (raw s_barrier+lgkmcnt --
// never __syncthreads, which drains vmcnt and would stall the 8 in-flight
// input loads). Round-3 lesson: no nontemporal hints (L3 residency).
// ---------------------------------------------------------------------------

#define D_DIM 4096

typedef float f32x4 __attribute__((ext_vector_type(4)));
typedef int i32x4 __attribute__((ext_vector_type(4)));

// ---- compile-time Threefry-2x32(20 rounds, key=(0,42)) keep-bit table ----
constexpr uint32_t rotl_c(uint32_t v, int n) {
  return (v << n) | (v >> (32 - n));
}

constexpr uint32_t tf_bits(uint32_t i) {
  const uint32_t ks0 = 0u, ks1 = 42u, ks2 = 0u ^ 42u ^ 0x1BD11BDAu;
  uint32_t x0 = 0u + ks0, x1 = i + ks1;
  // 5 groups of 4 rounds, rotation sets [13,15,26,6] / [17,29,16,24]
  x0 += x1; x1 = rotl_c(x1, 13); x1 ^= x0;
  x0 += x1; x1 = rotl_c(x1, 15); x1 ^= x0;
  x0 += x1; x1 = rotl_c(x1, 26); x1 ^= x0;
  x0 += x1; x1 = rotl_c(x1, 6);  x1 ^= x0;
  x0 += ks1; x1 += ks2 + 1u;
  x0 += x1; x1 = rotl_c(x1, 17); x1 ^= x0;
  x0 += x1; x1 = rotl_c(x1, 29); x1 ^= x0;
  x0 += x1; x1 = rotl_c(x1, 16); x1 ^= x0;
  x0 += x1; x1 = rotl_c(x1, 24); x1 ^= x0;
  x0 += ks2; x1 += ks0 + 2u;
  x0 += x1; x1 = rotl_c(x1, 13); x1 ^= x0;
  x0 += x1; x1 = rotl_c(x1, 15); x1 ^= x0;
  x0 += x1; x1 = rotl_c(x1, 26); x1 ^= x0;
  x0 += x1; x1 = rotl_c(x1, 6);  x1 ^= x0;
  x0 += ks0; x1 += ks1 + 3u;
  x0 += x1; x1 = rotl_c(x1, 17); x1 ^= x0;
  x0 += x1; x1 = rotl_c(x1, 29); x1 ^= x0;
  x0 += x1; x1 = rotl_c(x1, 16); x1 ^= x0;
  x0 += x1; x1 = rotl_c(x1, 24); x1 ^= x0;
  x0 += ks1; x1 += ks2 + 4u;
  x0 += x1; x1 = rotl_c(x1, 13); x1 ^= x0;
  x0 += x1; x1 = rotl_c(x1, 15); x1 ^= x0;
  x0 += x1; x1 = rotl_c(x1, 26); x1 ^= x0;
  x0 += x1; x1 = rotl_c(x1, 6);  x1 ^= x0;
  x0 += ks2; x1 += ks0 + 5u;
  return x0 ^ x1;
}

// keep <=> mantissa (bits>>9) >= 838861  (== !(u < 0.1f), exact)
constexpr uint32_t keep_word(int w) {
  uint32_t r = 0;
  for (int b = 0; b < 32; ++b) {
    if ((tf_bits((uint32_t)(w * 32 + b)) >> 9) >= 838861u) r |= (1u << b);
  }
  return r;
}

struct KeepTab {
  uint32_t w[64];
};
constexpr KeepTab make_tab() {
  KeepTab t{};
  for (int i = 0; i < 64; ++i) t.w[i] = keep_word(i);
  return t;
}
__device__ __constant__ KeepTab KEEP = make_tab();

// runtime keep for the generic fallback (any i)
__device__ __forceinline__ int keep_bit_rt(uint32_t i) {
  // same Threefry, runtime
  const uint32_t ks0 = 0u, ks1 = 42u, ks2 = 0u ^ 42u ^ 0x1BD11BDAu;
  uint32_t x0 = 0u + ks0, x1 = i + ks1;
#define TF4(a, b, c, d)                           \
  x0 += x1; x1 = (x1 << a) | (x1 >> (32 - a)); x1 ^= x0; \
  x0 += x1; x1 = (x1 << b) | (x1 >> (32 - b)); x1 ^= x0; \
  x0 += x1; x1 = (x1 << c) | (x1 >> (32 - c)); x1 ^= x0; \
  x0 += x1; x1 = (x1 << d) | (x1 >> (32 - d)); x1 ^= x0;
  TF4(13, 15, 26, 6)  x0 += ks1; x1 += ks2 + 1u;
  TF4(17, 29, 16, 24) x0 += ks2; x1 += ks0 + 2u;
  TF4(13, 15, 26, 6)  x0 += ks0; x1 += ks1 + 3u;
  TF4(17, 29, 16, 24) x0 += ks1; x1 += ks2 + 4u;
  TF4(13, 15, 26, 6)  x0 += ks2; x1 += ks0 + 5u;
#undef TF4
  return ((x0 ^ x1) >> 9) >= 838861u ? 1 : 0;
}

__global__ __launch_bounds__(512) void selective_dropout_fused(
    const f32x4* __restrict__ in, const int* __restrict__ idx, int n,
    f32x4* __restrict__ out, int total4) {
  // fast path: winner array for this block's half of D (2048 columns)
  __shared__ int lds[D_DIM];  // fast path uses [0..2047]; fallback all 4096
  const int t = threadIdx.x;
  const int tid = blockIdx.x * 512 + t;
  const int stride = gridDim.x * 512;
  const float inv_keep = (float)(1.0 / (1.0 - 0.1));

  if (n == 2048 && total4 == stride * 8 && gridDim.x == 1024) {
    int* packed = lds;             // [2048] max (i<<1 | keep); -1 untouched
    const int half = blockIdx.x & 1;  // block covers cols [half*2048, +2048)

    // --- A: idx slice + keep-table word first (oldest vmem) ---
    i32x4 c = ((const i32x4*)idx)[t];        // i = 4t..4t+3
    uint32_t kw = KEEP.w[t >> 3];            // one word covers 4t..4t+3
    __builtin_amdgcn_sched_barrier(0);

    // --- B: issue all 8 input loads (in flight through the head) ---
    f32x4 v[8];
#pragma unroll
    for (int k = 0; k < 8; ++k) v[k] = in[tid + k * stride];
    __builtin_amdgcn_sched_barrier(0);

    // --- C: init winner array (1 ds_write_b128 per thread) ---
    {
      i32x4 m1;
      m1[0] = -1; m1[1] = -1; m1[2] = -1; m1[3] = -1;
      ((i32x4*)packed)[t] = m1;
    }
    asm volatile("s_waitcnt lgkmcnt(0)" ::: "memory");
    __builtin_amdgcn_s_barrier();  // LDS-only; input loads stay in flight

    // --- D: direct filtered scatter (no hash: keep bit from table) ---
#pragma unroll
    for (int k = 0; k < 4; ++k) {
      int i = t * 4 + k;
      int d = c[k];
      if ((d >> 11) == half) {
        int keep = (int)((kw >> ((i & 31))) & 1u);
        atomicMax(&packed[d & 2047], (i << 1) | keep);
      }
    }
    asm volatile("s_waitcnt lgkmcnt(0)" ::: "memory");
    __builtin_amdgcn_s_barrier();

    // --- E: per-thread scale: local f32x4 index == t ---
    i32x4 pk = ((i32x4*)packed)[t];
    f32x4 s;
#pragma unroll
    for (int j = 0; j < 4; ++j)
      s[j] = (pk[j] < 0) ? 1.0f : ((pk[j] & 1) ? inv_keep : 0.0f);

    // --- F: multiply + store as loads land ---
#pragma unroll
    for (int k = 0; k < 8; ++k) {
      v[k] *= s;
      out[tid + k * stride] = v[k];
    }
  } else {
    // Generic fallback: full 4096-entry scatter, grid-stride apply.
    int* packed = lds;
    for (int d = t; d < D_DIM; d += blockDim.x) packed[d] = -1;
    __syncthreads();
    for (int i = t; i < n; i += blockDim.x) {
      atomicMax(&packed[idx[i]], (i << 1) | keep_bit_rt((uint32_t)i));
    }
    __syncthreads();
    const int gstride = gridDim.x * blockDim.x;
    for (int e = blockIdx.x * blockDim.x + t; e < total4; e += gstride) {
      i32x4 pk = ((i32x4*)packed)[e & (D_DIM / 4 - 1)];
      f32x4 s;
#pragma unroll
      for (int j = 0; j < 4; ++j)
        s[j] = (pk[j] < 0) ? 1.0f : ((pk[j] & 1) ? inv_keep : 0.0f);
      f32x4 x = in[e];
      x *= s;
      out[e] = x;
    }
  }
}

extern "C" void kernel_launch(void* const* d_in, const int* in_sizes, int n_in,
                              void* d_out, int out_size, void* d_ws, size_t ws_size,
                              hipStream_t stream) {
  const float* in = (const float*)d_in[0];
  const int* idx = (const int*)d_in[1];
  float* out = (float*)d_out;

  const int n_idx = in_sizes[1];    // 2048
  const int total = in_sizes[0];    // B*D = 16,777,216
  const int total4 = total / 4;

  const int blocks = 1024;  // 512 threads: 4 blocks/CU -> exactly resident
  hipLaunchKernelGGL(selective_dropout_fused, dim3(blocks), dim3(512), 0,
                     stream, (const f32x4*)in, idx, n_idx, (f32x4*)out,
                     total4);
}

// Round 8
// 25.028 us; speedup vs baseline: 1.4753x; 1.0781x over previous
//
#include <hip/hip_runtime.h>
#include <stdint.h>

// ---------------------------------------------------------------------------
// SelectiveDropout, fused single-kernel, compile-time RNG table, deep-MLP.
//   out[b,d] = in[b,d] * scale[d]
//   scale[d] = 1 unless d in neuron_indices; listed columns get
//   (u < 0.1) ? 0 : 1/0.9, u = jax.random.uniform(key(42), (2048,)),
//   duplicates last-write-wins.
//
// keep_bit(i) depends only on i -> constexpr Threefry table (64 words),
// integer-folded compare: u < 0.1f <=> (bits>>9) <= 838860. Bit-exact vs
// jax verified rounds 1-7 (absmax 0.0).
//
// Round-8 experiment: 512 blocks x 512 threads x 16 f32x4/thread
// (was 1024 x 512 x 8). Distinguishes latency-limited (deeper MLP helps)
// from fabric-BW-limited (null -> roofline). Half the redundant heads.
// __launch_bounds__(512,4): cap VGPR <= 128 so 2 blocks/CU stay resident.
//
// Block b covers scale cols [(b&1)*2048, +2048): grid stride 262144 == 0
// mod 1024, tid&1023 = (b&1)*512 + t. Input loads all issued before the
// head; LDS-only barriers (raw s_barrier + lgkmcnt(0), never __syncthreads
// which drains vmcnt). Round-3 lesson: no nontemporal hints (L3 residency).
// ---------------------------------------------------------------------------

#define D_DIM 4096

typedef float f32x4 __attribute__((ext_vector_type(4)));
typedef int i32x4 __attribute__((ext_vector_type(4)));

// ---- compile-time Threefry-2x32(20 rounds, key=(0,42)) keep-bit table ----
constexpr uint32_t rotl_c(uint32_t v, int n) {
  return (v << n) | (v >> (32 - n));
}

constexpr uint32_t tf_bits(uint32_t i) {
  const uint32_t ks0 = 0u, ks1 = 42u, ks2 = 0u ^ 42u ^ 0x1BD11BDAu;
  uint32_t x0 = 0u + ks0, x1 = i + ks1;
  x0 += x1; x1 = rotl_c(x1, 13); x1 ^= x0;
  x0 += x1; x1 = rotl_c(x1, 15); x1 ^= x0;
  x0 += x1; x1 = rotl_c(x1, 26); x1 ^= x0;
  x0 += x1; x1 = rotl_c(x1, 6);  x1 ^= x0;
  x0 += ks1; x1 += ks2 + 1u;
  x0 += x1; x1 = rotl_c(x1, 17); x1 ^= x0;
  x0 += x1; x1 = rotl_c(x1, 29); x1 ^= x0;
  x0 += x1; x1 = rotl_c(x1, 16); x1 ^= x0;
  x0 += x1; x1 = rotl_c(x1, 24); x1 ^= x0;
  x0 += ks2; x1 += ks0 + 2u;
  x0 += x1; x1 = rotl_c(x1, 13); x1 ^= x0;
  x0 += x1; x1 = rotl_c(x1, 15); x1 ^= x0;
  x0 += x1; x1 = rotl_c(x1, 26); x1 ^= x0;
  x0 += x1; x1 = rotl_c(x1, 6);  x1 ^= x0;
  x0 += ks0; x1 += ks1 + 3u;
  x0 += x1; x1 = rotl_c(x1, 17); x1 ^= x0;
  x0 += x1; x1 = rotl_c(x1, 29); x1 ^= x0;
  x0 += x1; x1 = rotl_c(x1, 16); x1 ^= x0;
  x0 += x1; x1 = rotl_c(x1, 24); x1 ^= x0;
  x0 += ks1; x1 += ks2 + 4u;
  x0 += x1; x1 = rotl_c(x1, 13); x1 ^= x0;
  x0 += x1; x1 = rotl_c(x1, 15); x1 ^= x0;
  x0 += x1; x1 = rotl_c(x1, 26); x1 ^= x0;
  x0 += x1; x1 = rotl_c(x1, 6);  x1 ^= x0;
  x0 += ks2; x1 += ks0 + 5u;
  return x0 ^ x1;
}

// keep <=> mantissa (bits>>9) >= 838861  (== !(u < 0.1f), exact)
constexpr uint32_t keep_word(int w) {
  uint32_t r = 0;
  for (int b = 0; b < 32; ++b) {
    if ((tf_bits((uint32_t)(w * 32 + b)) >> 9) >= 838861u) r |= (1u << b);
  }
  return r;
}

struct KeepTab {
  uint32_t w[64];
};
constexpr KeepTab make_tab() {
  KeepTab t{};
  for (int i = 0; i < 64; ++i) t.w[i] = keep_word(i);
  return t;
}
__device__ __constant__ KeepTab KEEP = make_tab();

// runtime keep for the generic fallback (any i)
__device__ __forceinline__ int keep_bit_rt(uint32_t i) {
  const uint32_t ks0 = 0u, ks1 = 42u, ks2 = 0u ^ 42u ^ 0x1BD11BDAu;
  uint32_t x0 = 0u + ks0, x1 = i + ks1;
#define TF4(a, b, c, d)                           \
  x0 += x1; x1 = (x1 << a) | (x1 >> (32 - a)); x1 ^= x0; \
  x0 += x1; x1 = (x1 << b) | (x1 >> (32 - b)); x1 ^= x0; \
  x0 += x1; x1 = (x1 << c) | (x1 >> (32 - c)); x1 ^= x0; \
  x0 += x1; x1 = (x1 << d) | (x1 >> (32 - d)); x1 ^= x0;
  TF4(13, 15, 26, 6)  x0 += ks1; x1 += ks2 + 1u;
  TF4(17, 29, 16, 24) x0 += ks2; x1 += ks0 + 2u;
  TF4(13, 15, 26, 6)  x0 += ks0; x1 += ks1 + 3u;
  TF4(17, 29, 16, 24) x0 += ks1; x1 += ks2 + 4u;
  TF4(13, 15, 26, 6)  x0 += ks2; x1 += ks0 + 5u;
#undef TF4
  return ((x0 ^ x1) >> 9) >= 838861u ? 1 : 0;
}

__global__ __launch_bounds__(512, 4) void selective_dropout_fused(
    const f32x4* __restrict__ in, const int* __restrict__ idx, int n,
    f32x4* __restrict__ out, int total4) {
  __shared__ int lds[D_DIM];  // fast path uses [0..2047]; fallback all 4096
  const int t = threadIdx.x;
  const int tid = blockIdx.x * 512 + t;
  const int stride = gridDim.x * 512;
  const float inv_keep = (float)(1.0 / (1.0 - 0.1));

  if (n == 2048 && total4 == stride * 16 && gridDim.x == 512) {
    int* packed = lds;                // [2048] max (i<<1|keep); -1 untouched
    const int half = blockIdx.x & 1;  // block covers cols [half*2048, +2048)

    // --- A: idx slice + keep-table word first (oldest vmem) ---
    i32x4 c = ((const i32x4*)idx)[t];  // i = 4t..4t+3
    uint32_t kw = KEEP.w[t >> 3];      // one word covers 4t..4t+3
    __builtin_amdgcn_sched_barrier(0);

    // --- B: issue all 16 input loads (stay in flight through the head) ---
    f32x4 v[16];
#pragma unroll
    for (int k = 0; k < 16; ++k) v[k] = in[tid + k * stride];
    __builtin_amdgcn_sched_barrier(0);

    // --- C: init winner array (1 ds_write_b128 per thread) ---
    {
      i32x4 m1;
      m1[0] = -1; m1[1] = -1; m1[2] = -1; m1[3] = -1;
      ((i32x4*)packed)[t] = m1;
    }
    asm volatile("s_waitcnt lgkmcnt(0)" ::: "memory");
    __builtin_amdgcn_s_barrier();  // LDS-only; input loads stay in flight

    // --- D: direct filtered scatter (keep bit from table, no hash) ---
#pragma unroll
    for (int k = 0; k < 4; ++k) {
      int i = t * 4 + k;
      int d = c[k];
      if ((d >> 11) == half) {
        int keep = (int)((kw >> (i & 31)) & 1u);
        atomicMax(&packed[d & 2047], (i << 1) | keep);
      }
    }
    asm volatile("s_waitcnt lgkmcnt(0)" ::: "memory");
    __builtin_amdgcn_s_barrier();

    // --- E: per-thread scale: local f32x4 index == t ---
    i32x4 pk = ((i32x4*)packed)[t];
    f32x4 s;
#pragma unroll
    for (int j = 0; j < 4; ++j)
      s[j] = (pk[j] < 0) ? 1.0f : ((pk[j] & 1) ? inv_keep : 0.0f);

    // --- F: multiply + store as loads land (vmcnt drains in order) ---
#pragma unroll
    for (int k = 0; k < 16; ++k) {
      v[k] *= s;
      out[tid + k * stride] = v[k];
    }
  } else {
    // Generic fallback: full 4096-entry scatter, grid-stride apply.
    int* packed = lds;
    for (int d = t; d < D_DIM; d += blockDim.x) packed[d] = -1;
    __syncthreads();
    for (int i = t; i < n; i += blockDim.x) {
      atomicMax(&packed[idx[i]], (i << 1) | keep_bit_rt((uint32_t)i));
    }
    __syncthreads();
    const int gstride = gridDim.x * blockDim.x;
    for (int e = blockIdx.x * blockDim.x + t; e < total4; e += gstride) {
      i32x4 pk = ((i32x4*)packed)[e & (D_DIM / 4 - 1)];
      f32x4 s;
#pragma unroll
      for (int j = 0; j < 4; ++j)
        s[j] = (pk[j] < 0) ? 1.0f : ((pk[j] & 1) ? inv_keep : 0.0f);
      f32x4 x = in[e];
      x *= s;
      out[e] = x;
    }
  }
}

extern "C" void kernel_launch(void* const* d_in, const int* in_sizes, int n_in,
                              void* d_out, int out_size, void* d_ws, size_t ws_size,
                              hipStream_t stream) {
  const float* in = (const float*)d_in[0];
  const int* idx = (const int*)d_in[1];
  float* out = (float*)d_out;

  const int n_idx = in_sizes[1];    // 2048
  const int total = in_sizes[0];    // B*D = 16,777,216
  const int total4 = total / 4;

  const int blocks = 512;  // 512 threads, 16 f32x4/thread: 2 blocks/CU
  hipLaunchKernelGGL(selective_dropout_fused, dim3(blocks), dim3(512), 0,
                     stream, (const f32x4*)in, idx, n_idx, (f32x4*)out,
                     total4);
}